// Round 3
// baseline (109.061 us; speedup 1.0000x reference)
//
#include <hip/hip_runtime.h>

#define TT 256
#define BB 256
#define DD 128
// out: outs[TT][BB][128] then hx[BB][128] then cx[BB][128]

__device__ __forceinline__ float frcp(float x) { return __builtin_amdgcn_rcpf(x); }
__device__ __forceinline__ float fastcos(float z) {
    float r = z * 0.15915494309189535f;      // radians -> revolutions
    r = __builtin_amdgcn_fractf(r);          // exact periodic reduction
    return __builtin_amdgcn_cosf(r);         // v_cos_f32 (revolutions)
}
// broadcast lane (quad_base+J) to all 4 lanes of each quad, pure-VALU DPP
template<int J>
__device__ __forceinline__ float quad_bcast(float v) {
    int i = __float_as_int(v);
    int r = __builtin_amdgcn_update_dpp(i, i, J * 0x55, 0xF, 0xF, false);
    return __int_as_float(r);
}

// Kernel 1: A[t*BB + b] = {a_f, a_i, a_u, a_o},  a_g = x[t,b,:] . Wg[0,0:128] + bg[0] + pg[0]
__global__ __launch_bounds__(256) void k_angles(
    const float* __restrict__ x,
    const float* __restrict__ Wf, const float* __restrict__ bf, const float* __restrict__ pf,
    const float* __restrict__ Wi, const float* __restrict__ bi, const float* __restrict__ pi,
    const float* __restrict__ Wu, const float* __restrict__ bu, const float* __restrict__ pu,
    const float* __restrict__ Wo, const float* __restrict__ bo, const float* __restrict__ po,
    float4* __restrict__ A)
{
    __shared__ float4 w4[4][32];             // row 0, cols 0..127 of each W
    float* w = reinterpret_cast<float*>(w4);
    int tid = threadIdx.x;
    for (int k = tid; k < 512; k += 256) {
        int g = k >> 7, j = k & 127;
        const float* W = (g == 0) ? Wf : (g == 1) ? Wi : (g == 2) ? Wu : Wo;
        w[g * 128 + j] = W[j];
    }
    __syncthreads();

    int r = blockIdx.x * 256 + tid;          // r = t*BB + b
    const float4* xr = reinterpret_cast<const float4*>(x + (size_t)r * DD);

    float af = bf[0] + pf[0];
    float ai = bi[0] + pi[0];
    float au = bu[0] + pu[0];
    float ao = bo[0] + po[0];
    #pragma unroll
    for (int k = 0; k < 32; ++k) {
        float4 v  = xr[k];
        float4 f4 = w4[0][k], i4 = w4[1][k], u4 = w4[2][k], o4 = w4[3][k];
        af = fmaf(v.x, f4.x, fmaf(v.y, f4.y, fmaf(v.z, f4.z, fmaf(v.w, f4.w, af))));
        ai = fmaf(v.x, i4.x, fmaf(v.y, i4.y, fmaf(v.z, i4.z, fmaf(v.w, i4.w, ai))));
        au = fmaf(v.x, u4.x, fmaf(v.y, u4.y, fmaf(v.z, u4.z, fmaf(v.w, u4.w, au))));
        ao = fmaf(v.x, o4.x, fmaf(v.y, o4.y, fmaf(v.z, o4.z, fmaf(v.w, o4.w, ao))));
    }
    A[r] = make_float4(af, ai, au, ao);      // coalesced [t][b] store
}

// Kernel 2: quad-per-sample recurrence + fused broadcast store.
// 16 blocks x 64 lanes; lane = (sample_in_wave<<2) | gate. Per quad, all 4 lanes
// end each step holding the same (c, h) via DPP quad broadcasts.
// Gate math: act = A*tanh(mu*cos(z)) + B  (sigma(v)=0.5+0.5*tanh(v/2)),
// tanh via exact Pade/continued-fraction (no exp): only 3 trans issues/step.
__global__ __launch_bounds__(64) void k_recur(
    const float* __restrict__ Af,            // A viewed as floats: (t*BB+s)*4 + g
    const float* __restrict__ Wf, const float* __restrict__ Wi,
    const float* __restrict__ Wu, const float* __restrict__ Wo,
    float* __restrict__ out)
{
    int lane = threadIdx.x;
    int q = lane >> 2;                       // quad 0..15
    int g = lane & 3;                        // gate f,i,u,o
    int s = blockIdx.x * 16 + q;             // sample

    // S_g = sum Wg[0,128:256] (h constant over hidden dim -> scalar feedback)
    const float* W = (g == 0) ? Wf : (g == 1) ? Wi : (g == 2) ? Wu : Wo;
    const float4* W4 = reinterpret_cast<const float4*>(W + 128);
    float S = 0.f;
    #pragma unroll
    for (int k = 0; k < 32; ++k) {
        float4 v = W4[k];
        S += (v.x + v.y) + (v.z + v.w);
    }
    float mu   = (g == 2) ? 1.f : 0.5f;      // tanh-gate vs sigmoid-gates
    float Aact = (g == 2) ? 1.f : 0.5f;
    float Bact = (g == 2) ? 0.f : 0.5f;

    const float* Ab = Af + (s * 4 + g);      // element t at Ab[t*1024]
    float* outRow = out + (size_t)s * 128 + g * 32;  // lane's 32-float slice of the bcast row
    float h = 0.f, c = 0.f;

    // prefetch depth 8 (named regs; runtime-indexed arrays would go to scratch)
    float p0 = Ab[0*1024], p1 = Ab[1*1024], p2 = Ab[2*1024], p3 = Ab[3*1024];
    float p4 = Ab[4*1024], p5 = Ab[5*1024], p6 = Ab[6*1024], p7 = Ab[7*1024];

#define STEP(P, TIDX)                                                         \
    {                                                                         \
        float z = fmaf(h, S, P);                                              \
        float v = fastcos(z);                                                 \
        float y = mu * v;                    /* |y| <= 1 */                   \
        float w = y * y;                                                      \
        float n = y * fmaf(w, 10.f, 105.f);                                   \
        float d = fmaf(w, w + 45.f, 105.f);                                   \
        float act = fmaf(Aact, n * frcp(d), Bact);                            \
        float tf = quad_bcast<0>(act);                                        \
        float ti = quad_bcast<1>(act);                                        \
        float tu = quad_bcast<2>(act);                                        \
        float to = quad_bcast<3>(act);                                        \
        c = fmaf(tf, c, ti * tu);            /* |c| <= 2.08 */                \
        float w2 = c * c;                                                     \
        float n2 = c * fmaf(w2, fmaf(w2, 21.f, 1260.f), 10395.f);             \
        float d2 = fmaf(w2, fmaf(w2, w2 + 210.f, 4725.f), 10395.f);           \
        float th = n2 * frcp(d2);                                             \
        h = to * th;                                                          \
        float4 hv = make_float4(h, h, h, h);                                  \
        float4* op = reinterpret_cast<float4*>(outRow + (size_t)(TIDX) * (BB * 128)); \
        op[0] = hv; op[1] = hv; op[2] = hv; op[3] = hv;                       \
        op[4] = hv; op[5] = hv; op[6] = hv; op[7] = hv;                       \
    }

    for (int t = 0; t < TT; t += 8) {
        int tn = t + 8;
        STEP(p0, t + 0); p0 = Ab[(size_t)min(tn + 0, TT - 1) * 1024];
        STEP(p1, t + 1); p1 = Ab[(size_t)min(tn + 1, TT - 1) * 1024];
        STEP(p2, t + 2); p2 = Ab[(size_t)min(tn + 2, TT - 1) * 1024];
        STEP(p3, t + 3); p3 = Ab[(size_t)min(tn + 3, TT - 1) * 1024];
        STEP(p4, t + 4); p4 = Ab[(size_t)min(tn + 4, TT - 1) * 1024];
        STEP(p5, t + 5); p5 = Ab[(size_t)min(tn + 5, TT - 1) * 1024];
        STEP(p6, t + 6); p6 = Ab[(size_t)min(tn + 6, TT - 1) * 1024];
        STEP(p7, t + 7); p7 = Ab[(size_t)min(tn + 7, TT - 1) * 1024];
    }
#undef STEP

    // hx, cx
    float* hx = out + (size_t)TT * BB * 128;
    float4* hp = reinterpret_cast<float4*>(hx + (size_t)s * 128 + g * 32);
    float4* cp = reinterpret_cast<float4*>(hx + (size_t)BB * 128 + (size_t)s * 128 + g * 32);
    float4 hv = make_float4(h, h, h, h);
    float4 cv = make_float4(c, c, c, c);
    #pragma unroll
    for (int k = 0; k < 8; ++k) { hp[k] = hv; cp[k] = cv; }
}

extern "C" void kernel_launch(void* const* d_in, const int* in_sizes, int n_in,
                              void* d_out, int out_size, void* d_ws, size_t ws_size,
                              hipStream_t stream) {
    const float* x = (const float*)d_in[0];
    const float *Wf, *bf, *pf, *Wi, *bi, *pi, *Wu, *bu, *pu, *Wo, *bo, *po;
    if (n_in >= 13 && in_sizes[3] == 8 && in_sizes[4] == 2048) {
        // setup_inputs dict order: (Wf,bf,pf),(Wi,bi,pi),(Wu,bu,pu),(Wo,bo,po)
        Wf = (const float*)d_in[1];  bf = (const float*)d_in[2];  pf = (const float*)d_in[3];
        Wi = (const float*)d_in[4];  bi = (const float*)d_in[5];  pi = (const float*)d_in[6];
        Wu = (const float*)d_in[7];  bu = (const float*)d_in[8];  pu = (const float*)d_in[9];
        Wo = (const float*)d_in[10]; bo = (const float*)d_in[11]; po = (const float*)d_in[12];
    } else {
        // reference signature order: Wf,bf,Wi,bi,Wu,bu,Wo,bo,pf,pi,pu,po
        Wf = (const float*)d_in[1];  bf = (const float*)d_in[2];
        Wi = (const float*)d_in[3];  bi = (const float*)d_in[4];
        Wu = (const float*)d_in[5];  bu = (const float*)d_in[6];
        Wo = (const float*)d_in[7];  bo = (const float*)d_in[8];
        pf = (const float*)d_in[9];  pi = (const float*)d_in[10];
        pu = (const float*)d_in[11]; po = (const float*)d_in[12];
    }
    float4* A = (float4*)d_ws;                 // 65536 * 16B = 1 MiB scratch

    k_angles<<<dim3(256), dim3(256), 0, stream>>>(
        x, Wf, bf, pf, Wi, bi, pi, Wu, bu, pu, Wo, bo, po, A);
    k_recur<<<dim3(16), dim3(64), 0, stream>>>(
        (const float*)A, Wf, Wi, Wu, Wo, (float*)d_out);
}

// Round 5
// 86.906 us; speedup vs baseline: 1.2549x; 1.2549x over previous
//
#include <hip/hip_runtime.h>

#define TT 256
#define BB 256
#define DD 128
#define INV2PI 0.15915494309189535f
// out: outs[TT][BB][128] then hx[BB][128] then cx[BB][128]

__device__ __forceinline__ float frcp(float x) { return __builtin_amdgcn_rcpf(x); }
__device__ __forceinline__ float rdlane(float v, int l) {
    return __int_as_float(__builtin_amdgcn_readlane(__float_as_int(v), l));
}
// broadcast lane (quad_base+J) to all 4 lanes of each quad (pure-VALU DPP)
template<int J>
__device__ __forceinline__ float quad_bcast(float v) {
    int i = __float_as_int(v);
    return __int_as_float(__builtin_amdgcn_update_dpp(i, i, J * 0x55, 0xF, 0xF, false));
}

// Kernel 1: A[t*BB+b] = angles/(2pi): a_g = (x[t,b,:].Wg[0,0:128] + bg[0] + pg[0]) / 2pi
__global__ __launch_bounds__(256) void k_angles(
    const float* __restrict__ x,
    const float* __restrict__ Wf, const float* __restrict__ bf, const float* __restrict__ pf,
    const float* __restrict__ Wi, const float* __restrict__ bi, const float* __restrict__ pi,
    const float* __restrict__ Wu, const float* __restrict__ bu, const float* __restrict__ pu,
    const float* __restrict__ Wo, const float* __restrict__ bo, const float* __restrict__ po,
    float4* __restrict__ A)
{
    __shared__ float4 w4[4][32];             // row 0, cols 0..127 of each W, pre-scaled
    float* w = reinterpret_cast<float*>(w4);
    int tid = threadIdx.x;
    for (int k = tid; k < 512; k += 256) {
        int g = k >> 7, j = k & 127;
        const float* W = (g == 0) ? Wf : (g == 1) ? Wi : (g == 2) ? Wu : Wo;
        w[g * 128 + j] = W[j] * INV2PI;
    }
    __syncthreads();

    int r = blockIdx.x * 256 + tid;          // r = t*BB + b
    const float4* xr = reinterpret_cast<const float4*>(x + (size_t)r * DD);

    float af = (bf[0] + pf[0]) * INV2PI;
    float ai = (bi[0] + pi[0]) * INV2PI;
    float au = (bu[0] + pu[0]) * INV2PI;
    float ao = (bo[0] + po[0]) * INV2PI;
    #pragma unroll
    for (int k = 0; k < 32; ++k) {
        float4 v  = xr[k];
        float4 f4 = w4[0][k], i4 = w4[1][k], u4 = w4[2][k], o4 = w4[3][k];
        af = fmaf(v.x, f4.x, fmaf(v.y, f4.y, fmaf(v.z, f4.z, fmaf(v.w, f4.w, af))));
        ai = fmaf(v.x, i4.x, fmaf(v.y, i4.y, fmaf(v.z, i4.z, fmaf(v.w, i4.w, ai))));
        au = fmaf(v.x, u4.x, fmaf(v.y, u4.y, fmaf(v.z, u4.z, fmaf(v.w, u4.w, au))));
        ao = fmaf(v.x, o4.x, fmaf(v.y, o4.y, fmaf(v.z, o4.z, fmaf(v.w, o4.w, ao))));
    }
    A[r] = make_float4(af, ai, au, ao);      // coalesced [t][b] store
}

// Kernel 2: quad-per-sample recurrence, h saved to regs, coalesced chunk dumps.
// 16 blocks x 64 lanes; lane = (q<<2)|g; quad q owns sample blk*16+q.
// act = A*tanh(mu*cos(z)) + B via Pade (3 trans issues/step).
__global__ __launch_bounds__(64) void k_recur(
    const float* __restrict__ Af,            // A as floats: (t*BB+s)*4 + g
    const float* __restrict__ Wf, const float* __restrict__ Wi,
    const float* __restrict__ Wu, const float* __restrict__ Wo,
    float* __restrict__ out)
{
    int lane = threadIdx.x;
    int q = lane >> 2, g = lane & 3;
    int s = blockIdx.x * 16 + q;
    bool hi = (lane >= 32);

    // S_g = (sum Wg[0,128:256]) / 2pi  (h constant over hidden dim -> scalar feedback)
    const float* W = (g == 0) ? Wf : (g == 1) ? Wi : (g == 2) ? Wu : Wo;
    const float4* W4 = reinterpret_cast<const float4*>(W + 128);
    float S = 0.f;
    #pragma unroll
    for (int k = 0; k < 32; ++k) {
        float4 v = W4[k];
        S += (v.x + v.y) + (v.z + v.w);
    }
    S *= INV2PI;
    float mu   = (g == 2) ? 1.f : 0.5f;      // tanh-gate vs sigmoid-gates
    float Aact = (g == 2) ? 1.f : 0.5f;
    float Bact = (g == 2) ? 0.f : 0.5f;

    const float* Ab = Af + (s * 4 + g);      // element t at Ab[t*1024]
    float4* out4 = reinterpret_cast<float4*>(out);
    float h = 0.f, c = 0.f;
    float hs0, hs1, hs2, hs3, hs4, hs5, hs6, hs7;

    // prefetch depth 8 (named regs)
    float p0 = Ab[0*1024], p1 = Ab[1*1024], p2 = Ab[2*1024], p3 = Ab[3*1024];
    float p4 = Ab[4*1024], p5 = Ab[5*1024], p6 = Ab[6*1024], p7 = Ab[7*1024];

#define STEP(P, HS)                                                           \
    {                                                                         \
        float z = fmaf(h, S, P);             /* revolutions */                \
        float v = __builtin_amdgcn_cosf(__builtin_amdgcn_fractf(z));          \
        float y = mu * v;                    /* |y| <= 1 */                   \
        float w = y * y;                                                      \
        float n = y * fmaf(w, 10.f, 105.f);                                   \
        float d = fmaf(w, w + 45.f, 105.f);                                   \
        float act = fmaf(Aact, n * frcp(d), Bact);                            \
        float tf = quad_bcast<0>(act);                                        \
        float ti = quad_bcast<1>(act);                                        \
        float tu = quad_bcast<2>(act);                                        \
        float to = quad_bcast<3>(act);                                        \
        c = fmaf(tf, c, ti * tu);            /* |c| <= 2.08 */                \
        float w2 = c * c;                                                     \
        float n2 = c * fmaf(w2, fmaf(w2, 21.f, 1260.f), 10395.f);             \
        float d2 = fmaf(w2, fmaf(w2, w2 + 210.f, 4725.f), 10395.f);           \
        h = to * (n2 * frcp(d2));                                             \
        HS = h;                                                               \
    }

// coalesced dump of one timestep: 8 x dwordx4, each = 64 lanes x 16B = 1KB contiguous.
// Store m covers this block's samples {2m, 2m+1} (float4s 64m..64m+63 of the block's
// 512-float4 range); h of sample 2m+hi is quad-uniform -> lanes 8m / 8m+4 hold it.
#define DUMPG(H, OBG)                                                          \
    {                                                                          \
        float a0, a1, vv;                                                      \
        a0=rdlane(H, 0); a1=rdlane(H, 4); vv=hi?a1:a0; (OBG)[0]  =make_float4(vv,vv,vv,vv); \
        a0=rdlane(H, 8); a1=rdlane(H,12); vv=hi?a1:a0; (OBG)[64] =make_float4(vv,vv,vv,vv); \
        a0=rdlane(H,16); a1=rdlane(H,20); vv=hi?a1:a0; (OBG)[128]=make_float4(vv,vv,vv,vv); \
        a0=rdlane(H,24); a1=rdlane(H,28); vv=hi?a1:a0; (OBG)[192]=make_float4(vv,vv,vv,vv); \
        a0=rdlane(H,32); a1=rdlane(H,36); vv=hi?a1:a0; (OBG)[256]=make_float4(vv,vv,vv,vv); \
        a0=rdlane(H,40); a1=rdlane(H,44); vv=hi?a1:a0; (OBG)[320]=make_float4(vv,vv,vv,vv); \
        a0=rdlane(H,48); a1=rdlane(H,52); vv=hi?a1:a0; (OBG)[384]=make_float4(vv,vv,vv,vv); \
        a0=rdlane(H,56); a1=rdlane(H,60); vv=hi?a1:a0; (OBG)[448]=make_float4(vv,vv,vv,vv); \
    }

    for (int t = 0; t < TT; t += 8) {
        int tn = t + 8;
        STEP(p0, hs0); p0 = Ab[(size_t)min(tn + 0, TT - 1) * 1024];
        STEP(p1, hs1); p1 = Ab[(size_t)min(tn + 1, TT - 1) * 1024];
        STEP(p2, hs2); p2 = Ab[(size_t)min(tn + 2, TT - 1) * 1024];
        STEP(p3, hs3); p3 = Ab[(size_t)min(tn + 3, TT - 1) * 1024];
        STEP(p4, hs4); p4 = Ab[(size_t)min(tn + 4, TT - 1) * 1024];
        STEP(p5, hs5); p5 = Ab[(size_t)min(tn + 5, TT - 1) * 1024];
        STEP(p6, hs6); p6 = Ab[(size_t)min(tn + 6, TT - 1) * 1024];
        STEP(p7, hs7); p7 = Ab[(size_t)min(tn + 7, TT - 1) * 1024];

        // dump t..t+7: timestep stride in float4s is 8192 (= BB*128/4)
        float4* ob = out4 + (size_t)t * 8192 + (size_t)blockIdx.x * 512 + lane;
        DUMPG(hs0, ob);            DUMPG(hs1, ob + 1 * 8192);
        DUMPG(hs2, ob + 2 * 8192); DUMPG(hs3, ob + 3 * 8192);
        DUMPG(hs4, ob + 4 * 8192); DUMPG(hs5, ob + 5 * 8192);
        DUMPG(hs6, ob + 6 * 8192); DUMPG(hs7, ob + 7 * 8192);
    }
#undef STEP

    // hx, cx (same coalesced pattern; cx is BB*128 floats = 8192 float4s after hx)
    float4* hxb = out4 + (size_t)2097152 + (size_t)blockIdx.x * 512 + lane;
    DUMPG(h, hxb);
    DUMPG(c, hxb + 8192);
#undef DUMPG
}

extern "C" void kernel_launch(void* const* d_in, const int* in_sizes, int n_in,
                              void* d_out, int out_size, void* d_ws, size_t ws_size,
                              hipStream_t stream) {
    const float* x = (const float*)d_in[0];
    const float *Wf, *bf, *pf, *Wi, *bi, *pi, *Wu, *bu, *pu, *Wo, *bo, *po;
    if (n_in >= 13 && in_sizes[3] == 8 && in_sizes[4] == 2048) {
        // setup_inputs dict order: (Wf,bf,pf),(Wi,bi,pi),(Wu,bu,pu),(Wo,bo,po)
        Wf = (const float*)d_in[1];  bf = (const float*)d_in[2];  pf = (const float*)d_in[3];
        Wi = (const float*)d_in[4];  bi = (const float*)d_in[5];  pi = (const float*)d_in[6];
        Wu = (const float*)d_in[7];  bu = (const float*)d_in[8];  pu = (const float*)d_in[9];
        Wo = (const float*)d_in[10]; bo = (const float*)d_in[11]; po = (const float*)d_in[12];
    } else {
        // reference signature order: Wf,bf,Wi,bi,Wu,bu,Wo,bo,pf,pi,pu,po
        Wf = (const float*)d_in[1];  bf = (const float*)d_in[2];
        Wi = (const float*)d_in[3];  bi = (const float*)d_in[4];
        Wu = (const float*)d_in[5];  bu = (const float*)d_in[6];
        Wo = (const float*)d_in[7];  bo = (const float*)d_in[8];
        pf = (const float*)d_in[9];  pi = (const float*)d_in[10];
        pu = (const float*)d_in[11]; po = (const float*)d_in[12];
    }
    float4* A = (float4*)d_ws;                 // 65536 * 16B = 1 MiB scratch

    k_angles<<<dim3(256), dim3(256), 0, stream>>>(
        x, Wf, bf, pf, Wi, bi, pi, Wu, bu, pu, Wo, bo, po, A);
    k_recur<<<dim3(16), dim3(64), 0, stream>>>(
        (const float*)A, Wf, Wi, Wu, Wo, (float*)d_out);
}

// Round 6
// 47.102 us; speedup vs baseline: 2.3154x; 1.8451x over previous
//
#include <hip/hip_runtime.h>

#define TT 256
#define BB 256
#define DD 128
#define INV2PI 0.15915494309189535f
// out: outs[TT][BB][128] then hx[BB][128] then cx[BB][128]

__device__ __forceinline__ float frcp(float x) { return __builtin_amdgcn_rcpf(x); }
// broadcast lane (quad_base+J) to all 4 lanes of each quad (pure-VALU DPP)
template<int J>
__device__ __forceinline__ float quad_bcast(float v) {
    int i = __float_as_int(v);
    return __int_as_float(__builtin_amdgcn_update_dpp(i, i, J * 0x55, 0xF, 0xF, false));
}

// Kernel 1: A[t*BB+b] = angles/(2pi): a_g = (x[t,b,:].Wg[0,0:128] + bg[0] + pg[0]) / 2pi
__global__ __launch_bounds__(256) void k_angles(
    const float* __restrict__ x,
    const float* __restrict__ Wf, const float* __restrict__ bf, const float* __restrict__ pf,
    const float* __restrict__ Wi, const float* __restrict__ bi, const float* __restrict__ pi,
    const float* __restrict__ Wu, const float* __restrict__ bu, const float* __restrict__ pu,
    const float* __restrict__ Wo, const float* __restrict__ bo, const float* __restrict__ po,
    float4* __restrict__ A)
{
    __shared__ float4 w4[4][32];             // row 0, cols 0..127 of each W, pre-scaled
    float* w = reinterpret_cast<float*>(w4);
    int tid = threadIdx.x;
    for (int k = tid; k < 512; k += 256) {
        int g = k >> 7, j = k & 127;
        const float* W = (g == 0) ? Wf : (g == 1) ? Wi : (g == 2) ? Wu : Wo;
        w[g * 128 + j] = W[j] * INV2PI;
    }
    __syncthreads();

    int r = blockIdx.x * 256 + tid;          // r = t*BB + b
    const float4* xr = reinterpret_cast<const float4*>(x + (size_t)r * DD);

    float af = (bf[0] + pf[0]) * INV2PI;
    float ai = (bi[0] + pi[0]) * INV2PI;
    float au = (bu[0] + pu[0]) * INV2PI;
    float ao = (bo[0] + po[0]) * INV2PI;
    #pragma unroll
    for (int k = 0; k < 32; ++k) {
        float4 v  = xr[k];
        float4 f4 = w4[0][k], i4 = w4[1][k], u4 = w4[2][k], o4 = w4[3][k];
        af = fmaf(v.x, f4.x, fmaf(v.y, f4.y, fmaf(v.z, f4.z, fmaf(v.w, f4.w, af))));
        ai = fmaf(v.x, i4.x, fmaf(v.y, i4.y, fmaf(v.z, i4.z, fmaf(v.w, i4.w, ai))));
        au = fmaf(v.x, u4.x, fmaf(v.y, u4.y, fmaf(v.z, u4.z, fmaf(v.w, u4.w, au))));
        ao = fmaf(v.x, o4.x, fmaf(v.y, o4.y, fmaf(v.z, o4.z, fmaf(v.w, o4.w, ao))));
    }
    A[r] = make_float4(af, ai, au, ao);      // coalesced [t][b] store
}

// Kernel 2: quad-per-sample recurrence, compact h stores into consumed A slots.
// 16 blocks x 64 lanes; lane = (q<<2)|g; quad q owns sample blk*16+q.
// act = Bact + v*(K0+K1*w) / (D0+D1*w+D2*w^2), w=v^2  (mu folded into Pade coeffs).
// Per step: 1 cos + 2 rcp trans; one coalesced 256B store (h into all 4 comps of A[t][s]).
__global__ __launch_bounds__(64) void k_recur(
    float* __restrict__ Af,                  // A as floats: (t*BB+s)*4 + g  (read+overwrite)
    const float* __restrict__ Wf, const float* __restrict__ Wi,
    const float* __restrict__ Wu, const float* __restrict__ Wo)
{
    int lane = threadIdx.x;
    int q = lane >> 2, g = lane & 3;
    int s = blockIdx.x * 16 + q;
    int s4g = s * 4 + g;

    // S_g = (sum Wg[0,128:256]) / 2pi  (h constant over hidden dim -> scalar feedback)
    const float* W = (g == 0) ? Wf : (g == 1) ? Wi : (g == 2) ? Wu : Wo;
    const float4* W4 = reinterpret_cast<const float4*>(W + 128);
    float S = 0.f;
    #pragma unroll
    for (int k = 0; k < 32; ++k) {
        float4 v = W4[k];
        S += (v.x + v.y) + (v.z + v.w);
    }
    S *= INV2PI;
    // tanh gate (g==2): act = tanh(v)          = v(105+10w)/(105+45w+w^2)
    // sigmoid gates:    act = 0.5+0.5*tanh(v/2) = 0.5 + v(26.25+0.625w)/(105+11.25w+0.0625w^2)
    bool tg = (g == 2);
    float K0 = tg ? 105.f : 26.25f;
    float K1 = tg ? 10.f  : 0.625f;
    float D1 = tg ? 45.f  : 11.25f;
    float D2 = tg ? 1.f   : 0.0625f;
    float Bact = tg ? 0.f : 0.5f;

    const float* Ab = Af + s4g;              // element t at Ab[t*1024]
    float h = 0.f, c = 0.f;

    // prefetch depth 8 (named regs)
    float p0 = Ab[0*1024], p1 = Ab[1*1024], p2 = Ab[2*1024], p3 = Ab[3*1024];
    float p4 = Ab[4*1024], p5 = Ab[5*1024], p6 = Ab[6*1024], p7 = Ab[7*1024];

#define STEPC(P)                                                              \
    {                                                                         \
        float z = fmaf(h, S, P);             /* revolutions */                \
        float v = __builtin_amdgcn_cosf(__builtin_amdgcn_fractf(z));          \
        float w = v * v;                                                      \
        float n = v * fmaf(w, K1, K0);                                        \
        float d = fmaf(w, fmaf(w, D2, D1), 105.f);                            \
        float act = fmaf(n, frcp(d), Bact);                                   \
        float tf = quad_bcast<0>(act);                                        \
        float ti = quad_bcast<1>(act);                                        \
        float tu = quad_bcast<2>(act);                                        \
        float to = quad_bcast<3>(act);                                        \
        c = fmaf(tf, c, ti * tu);            /* |c| <= 2.08 */                \
        float w2 = c * c;                                                     \
        float n2 = c * fmaf(w2, fmaf(w2, 21.f, 1260.f), 10395.f);             \
        float d2 = fmaf(w2, fmaf(w2, w2 + 210.f, 4725.f), 10395.f);           \
        h = to * (n2 * frcp(d2));                                             \
    }
// store h into all 4 components of A[t][s] (64 lanes x 4B = 256B coalesced; slot consumed)
#define STEP(P, TIDX) { STEPC(P); Af[(size_t)(TIDX) * 1024 + s4g] = h; }

    for (int t = 0; t < TT - 8; t += 8) {    // t = 0..240; prefetch tn+7 <= 255
        int tn = t + 8;
        STEP(p0, t + 0); p0 = Ab[(size_t)(tn + 0) * 1024];
        STEP(p1, t + 1); p1 = Ab[(size_t)(tn + 1) * 1024];
        STEP(p2, t + 2); p2 = Ab[(size_t)(tn + 2) * 1024];
        STEP(p3, t + 3); p3 = Ab[(size_t)(tn + 3) * 1024];
        STEP(p4, t + 4); p4 = Ab[(size_t)(tn + 4) * 1024];
        STEP(p5, t + 5); p5 = Ab[(size_t)(tn + 5) * 1024];
        STEP(p6, t + 6); p6 = Ab[(size_t)(tn + 6) * 1024];
        STEP(p7, t + 7); p7 = Ab[(size_t)(tn + 7) * 1024];
    }
    // final group t = 248..255; last slot gets {h, c} packed in one store (no ordering hazard)
    STEP(p0, 248); STEP(p1, 249); STEP(p2, 250); STEP(p3, 251);
    STEP(p4, 252); STEP(p5, 253); STEP(p6, 254);
    STEPC(p7);
    Af[(size_t)255 * 1024 + s4g] = (g == 1) ? c : h;   // A[255][s] = {h, c, h, h}
#undef STEP
#undef STEPC
}

// Kernel 3: broadcast expand. outs[t][b][:] = A[t*BB+b].x; hx[b][:] = A[255*BB+b].x;
// cx[b][:] = A[255*BB+b].y
__global__ __launch_bounds__(256) void k_expand(
    const float4* __restrict__ A, float4* __restrict__ out)
{
    unsigned r = blockIdx.x * 256 + threadIdx.x;          // one float4 of output
    const unsigned OUTS4 = (unsigned)TT * BB * 128 / 4;   // 2,097,152
    const unsigned HX4   = (unsigned)BB * 128 / 4;        // 8,192
    float v;
    if (r < OUTS4) {
        v = A[r >> 5].x;                                  // 32 float4 per (t,b)
    } else {
        unsigned qq = r - OUTS4;
        unsigned b = (qq & (HX4 - 1)) >> 5;
        float4 a = A[(TT - 1) * BB + b];
        v = (qq < HX4) ? a.x : a.y;
    }
    out[r] = make_float4(v, v, v, v);
}

extern "C" void kernel_launch(void* const* d_in, const int* in_sizes, int n_in,
                              void* d_out, int out_size, void* d_ws, size_t ws_size,
                              hipStream_t stream) {
    const float* x = (const float*)d_in[0];
    const float *Wf, *bf, *pf, *Wi, *bi, *pi, *Wu, *bu, *pu, *Wo, *bo, *po;
    if (n_in >= 13 && in_sizes[3] == 8 && in_sizes[4] == 2048) {
        // setup_inputs dict order: (Wf,bf,pf),(Wi,bi,pi),(Wu,bu,pu),(Wo,bo,po)
        Wf = (const float*)d_in[1];  bf = (const float*)d_in[2];  pf = (const float*)d_in[3];
        Wi = (const float*)d_in[4];  bi = (const float*)d_in[5];  pi = (const float*)d_in[6];
        Wu = (const float*)d_in[7];  bu = (const float*)d_in[8];  pu = (const float*)d_in[9];
        Wo = (const float*)d_in[10]; bo = (const float*)d_in[11]; po = (const float*)d_in[12];
    } else {
        // reference signature order: Wf,bf,Wi,bi,Wu,bu,Wo,bo,pf,pi,pu,po
        Wf = (const float*)d_in[1];  bf = (const float*)d_in[2];
        Wi = (const float*)d_in[3];  bi = (const float*)d_in[4];
        Wu = (const float*)d_in[5];  bu = (const float*)d_in[6];
        Wo = (const float*)d_in[7];  bo = (const float*)d_in[8];
        pf = (const float*)d_in[9];  pi = (const float*)d_in[10];
        pu = (const float*)d_in[11]; po = (const float*)d_in[12];
    }
    float4* A = (float4*)d_ws;                 // 65536 * 16B = 1 MiB scratch

    k_angles<<<dim3(256), dim3(256), 0, stream>>>(
        x, Wf, bf, pf, Wi, bi, pi, Wu, bu, pu, Wo, bo, po, A);
    k_recur<<<dim3(16), dim3(64), 0, stream>>>(
        (float*)A, Wf, Wi, Wu, Wo);
    k_expand<<<dim3((TT * BB * 128 / 4 + 2 * BB * 128 / 4) / 256), dim3(256), 0, stream>>>(
        A, (float4*)d_out);
}

// Round 7
// 46.481 us; speedup vs baseline: 2.3463x; 1.0134x over previous
//
#include <hip/hip_runtime.h>

#define TT 256
#define BB 256
#define DD 128
#define INV2PI 0.15915494309189535f
// out: outs[TT][BB][128] then hx[BB][128] then cx[BB][128]

__device__ __forceinline__ float frcp(float x) { return __builtin_amdgcn_rcpf(x); }
// broadcast lane (quad_base+J) to all 4 lanes of each quad (pure-VALU DPP)
template<int J>
__device__ __forceinline__ float quad_bcast(float v) {
    int i = __float_as_int(v);
    return __int_as_float(__builtin_amdgcn_update_dpp(i, i, J * 0x55, 0xF, 0xF, false));
}

// Kernel 1: A[t*BB+b] = angles/(2pi): a_g = (x[t,b,:].Wg[0,0:128] + bg[0] + pg[0]) / 2pi
__global__ __launch_bounds__(256) void k_angles(
    const float* __restrict__ x,
    const float* __restrict__ Wf, const float* __restrict__ bf, const float* __restrict__ pf,
    const float* __restrict__ Wi, const float* __restrict__ bi, const float* __restrict__ pi,
    const float* __restrict__ Wu, const float* __restrict__ bu, const float* __restrict__ pu,
    const float* __restrict__ Wo, const float* __restrict__ bo, const float* __restrict__ po,
    float4* __restrict__ A)
{
    __shared__ float4 w4[4][32];             // row 0, cols 0..127 of each W, pre-scaled
    float* w = reinterpret_cast<float*>(w4);
    int tid = threadIdx.x;
    for (int k = tid; k < 512; k += 256) {
        int g = k >> 7, j = k & 127;
        const float* W = (g == 0) ? Wf : (g == 1) ? Wi : (g == 2) ? Wu : Wo;
        w[g * 128 + j] = W[j] * INV2PI;
    }
    __syncthreads();

    int r = blockIdx.x * 256 + tid;          // r = t*BB + b
    const float4* xr = reinterpret_cast<const float4*>(x + (size_t)r * DD);

    float af = (bf[0] + pf[0]) * INV2PI;
    float ai = (bi[0] + pi[0]) * INV2PI;
    float au = (bu[0] + pu[0]) * INV2PI;
    float ao = (bo[0] + po[0]) * INV2PI;
    #pragma unroll
    for (int k = 0; k < 32; ++k) {
        float4 v  = xr[k];
        float4 f4 = w4[0][k], i4 = w4[1][k], u4 = w4[2][k], o4 = w4[3][k];
        af = fmaf(v.x, f4.x, fmaf(v.y, f4.y, fmaf(v.z, f4.z, fmaf(v.w, f4.w, af))));
        ai = fmaf(v.x, i4.x, fmaf(v.y, i4.y, fmaf(v.z, i4.z, fmaf(v.w, i4.w, ai))));
        au = fmaf(v.x, u4.x, fmaf(v.y, u4.y, fmaf(v.z, u4.z, fmaf(v.w, u4.w, au))));
        ao = fmaf(v.x, o4.x, fmaf(v.y, o4.y, fmaf(v.z, o4.z, fmaf(v.w, o4.w, ao))));
    }
    A[r] = make_float4(af, ai, au, ao);      // coalesced [t][b] store
}

// Kernel 2: quad-per-sample recurrence, compact h stores into consumed A slots.
// 16 blocks x 64 lanes; lane = (q<<2)|g; quad q owns sample blk*16+q.
// Chain per step: fma -> v_cos (revolutions, |z|<~2 << 256 HW domain, no fract)
// -> gate Pade rcp -> DPP bcast -> c fma -> tanh(c) Pade rcp -> h.
__global__ __launch_bounds__(64) void k_recur(
    float* __restrict__ Af,                  // A as floats: (t*BB+s)*4 + g  (read+overwrite)
    const float* __restrict__ Wf, const float* __restrict__ Wi,
    const float* __restrict__ Wu, const float* __restrict__ Wo)
{
    int lane = threadIdx.x;
    int q = lane >> 2, g = lane & 3;
    int s = blockIdx.x * 16 + q;
    int s4g = s * 4 + g;

    // S_g = (sum Wg[0,128:256]) / 2pi  (h constant over hidden dim -> scalar feedback)
    const float* W = (g == 0) ? Wf : (g == 1) ? Wi : (g == 2) ? Wu : Wo;
    const float4* W4 = reinterpret_cast<const float4*>(W + 128);
    float S = 0.f;
    #pragma unroll
    for (int k = 0; k < 32; ++k) {
        float4 v = W4[k];
        S += (v.x + v.y) + (v.z + v.w);
    }
    S *= INV2PI;
    // tanh gate (g==2): act = tanh(v)          = v(105+10w)/(105+45w+w^2)
    // sigmoid gates:    act = 0.5+0.5*tanh(v/2) = 0.5 + v(26.25+0.625w)/(105+11.25w+0.0625w^2)
    bool tg = (g == 2);
    float K0 = tg ? 105.f : 26.25f;
    float K1 = tg ? 10.f  : 0.625f;
    float D1 = tg ? 45.f  : 11.25f;
    float D2 = tg ? 1.f   : 0.0625f;
    float Bact = tg ? 0.f : 0.5f;

    const float* Ab = Af + s4g;              // element t at Ab[t*1024]
    float h = 0.f, c = 0.f;

    // prefetch depth 8 (named regs)
    float p0 = Ab[0*1024], p1 = Ab[1*1024], p2 = Ab[2*1024], p3 = Ab[3*1024];
    float p4 = Ab[4*1024], p5 = Ab[5*1024], p6 = Ab[6*1024], p7 = Ab[7*1024];

#define STEPC(P)                                                              \
    {                                                                         \
        float z = fmaf(h, S, P);             /* revolutions, |z| < ~2 */      \
        float v = __builtin_amdgcn_cosf(z);  /* HW domain +-256 rev */        \
        float w = v * v;                                                      \
        float d = fmaf(w, fmaf(w, D2, D1), 105.f);                            \
        float rd = frcp(d);                                                   \
        float n = v * fmaf(w, K1, K0);                                        \
        float act = fmaf(n, rd, Bact);                                        \
        float tu = quad_bcast<2>(act);       /* consumption order */          \
        float ti = quad_bcast<1>(act);                                        \
        float tf = quad_bcast<0>(act);                                        \
        float to = quad_bcast<3>(act);                                        \
        c = fmaf(tf, c, ti * tu);            /* |c| <= 2.08 */                \
        float w2 = c * c;                                                     \
        float d2 = fmaf(w2, fmaf(w2, w2 + 210.f, 4725.f), 10395.f);           \
        float rd2 = frcp(d2);                                                 \
        float n2 = c * fmaf(w2, fmaf(w2, 21.f, 1260.f), 10395.f);             \
        h = (to * n2) * rd2;                 /* to*n2 overlaps rcp */         \
    }
// store h into all 4 components of A[t][s] (64 lanes x 4B = 256B coalesced; slot consumed)
#define STEP(P, TIDX) { STEPC(P); Af[(size_t)(TIDX) * 1024 + s4g] = h; }

    for (int t = 0; t < TT - 8; t += 8) {    // t = 0..240; prefetch tn+7 <= 255
        int tn = t + 8;
        STEP(p0, t + 0); p0 = Ab[(size_t)(tn + 0) * 1024];
        STEP(p1, t + 1); p1 = Ab[(size_t)(tn + 1) * 1024];
        STEP(p2, t + 2); p2 = Ab[(size_t)(tn + 2) * 1024];
        STEP(p3, t + 3); p3 = Ab[(size_t)(tn + 3) * 1024];
        STEP(p4, t + 4); p4 = Ab[(size_t)(tn + 4) * 1024];
        STEP(p5, t + 5); p5 = Ab[(size_t)(tn + 5) * 1024];
        STEP(p6, t + 6); p6 = Ab[(size_t)(tn + 6) * 1024];
        STEP(p7, t + 7); p7 = Ab[(size_t)(tn + 7) * 1024];
    }
    // final group t = 248..255; last slot gets {h, c} packed in one store (no ordering hazard)
    STEP(p0, 248); STEP(p1, 249); STEP(p2, 250); STEP(p3, 251);
    STEP(p4, 252); STEP(p5, 253); STEP(p6, 254);
    STEPC(p7);
    Af[(size_t)255 * 1024 + s4g] = (g == 1) ? c : h;   // A[255][s] = {h, c, h, h}
#undef STEP
#undef STEPC
}

// Kernel 3: broadcast expand. outs[t][b][:] = A[t*BB+b].x; hx[b][:] = A[255*BB+b].x;
// cx[b][:] = A[255*BB+b].y
__global__ __launch_bounds__(256) void k_expand(
    const float4* __restrict__ A, float4* __restrict__ out)
{
    unsigned r = blockIdx.x * 256 + threadIdx.x;          // one float4 of output
    const unsigned OUTS4 = (unsigned)TT * BB * 128 / 4;   // 2,097,152
    const unsigned HX4   = (unsigned)BB * 128 / 4;        // 8,192
    float v;
    if (r < OUTS4) {
        v = A[r >> 5].x;                                  // 32 float4 per (t,b)
    } else {
        unsigned qq = r - OUTS4;
        unsigned b = (qq & (HX4 - 1)) >> 5;
        float4 a = A[(TT - 1) * BB + b];
        v = (qq < HX4) ? a.x : a.y;
    }
    out[r] = make_float4(v, v, v, v);
}

extern "C" void kernel_launch(void* const* d_in, const int* in_sizes, int n_in,
                              void* d_out, int out_size, void* d_ws, size_t ws_size,
                              hipStream_t stream) {
    const float* x = (const float*)d_in[0];
    const float *Wf, *bf, *pf, *Wi, *bi, *pi, *Wu, *bu, *pu, *Wo, *bo, *po;
    if (n_in >= 13 && in_sizes[3] == 8 && in_sizes[4] == 2048) {
        // setup_inputs dict order: (Wf,bf,pf),(Wi,bi,pi),(Wu,bu,pu),(Wo,bo,po)
        Wf = (const float*)d_in[1];  bf = (const float*)d_in[2];  pf = (const float*)d_in[3];
        Wi = (const float*)d_in[4];  bi = (const float*)d_in[5];  pi = (const float*)d_in[6];
        Wu = (const float*)d_in[7];  bu = (const float*)d_in[8];  pu = (const float*)d_in[9];
        Wo = (const float*)d_in[10]; bo = (const float*)d_in[11]; po = (const float*)d_in[12];
    } else {
        // reference signature order: Wf,bf,Wi,bi,Wu,bu,Wo,bo,pf,pi,pu,po
        Wf = (const float*)d_in[1];  bf = (const float*)d_in[2];
        Wi = (const float*)d_in[3];  bi = (const float*)d_in[4];
        Wu = (const float*)d_in[5];  bu = (const float*)d_in[6];
        Wo = (const float*)d_in[7];  bo = (const float*)d_in[8];
        pf = (const float*)d_in[9];  pi = (const float*)d_in[10];
        pu = (const float*)d_in[11]; po = (const float*)d_in[12];
    }
    float4* A = (float4*)d_ws;                 // 65536 * 16B = 1 MiB scratch

    k_angles<<<dim3(256), dim3(256), 0, stream>>>(
        x, Wf, bf, pf, Wi, bi, pi, Wu, bu, pu, Wo, bo, po, A);
    k_recur<<<dim3(16), dim3(64), 0, stream>>>(
        (float*)A, Wf, Wi, Wu, Wo);
    k_expand<<<dim3((TT * BB * 128 / 4 + 2 * BB * 128 / 4) / 256), dim3(256), 0, stream>>>(
        A, (float4*)d_out);
}

// Round 8
// 40.742 us; speedup vs baseline: 2.6769x; 1.1409x over previous
//
#include <hip/hip_runtime.h>

#define TT 256
#define BB 256
#define DD 128
#define INV2PI 0.15915494309189535f
// out: outs[TT][BB][128] then hx[BB][128] then cx[BB][128]
// ws: AT[256 samples][4 gates][256 t] floats (1 MiB). f-row doubles as H after consumption.

__device__ __forceinline__ float frcp(float x) { return __builtin_amdgcn_rcpf(x); }
// broadcast lane (quad_base+J) to all 4 lanes of each quad (pure-VALU DPP)
template<int J>
__device__ __forceinline__ float quad_bcast(float v) {
    int i = __float_as_int(v);
    return __int_as_float(__builtin_amdgcn_update_dpp(i, i, J * 0x55, 0xF, 0xF, false));
}

// Kernel 1: AT[(b*4+g)*256 + t] = (x[t,b,:].Wg[0,0:128] + bg[0] + pg[0]) / 2pi
__global__ __launch_bounds__(256) void k_angles(
    const float* __restrict__ x,
    const float* __restrict__ Wf, const float* __restrict__ bf, const float* __restrict__ pf,
    const float* __restrict__ Wi, const float* __restrict__ bi, const float* __restrict__ pi,
    const float* __restrict__ Wu, const float* __restrict__ bu, const float* __restrict__ pu,
    const float* __restrict__ Wo, const float* __restrict__ bo, const float* __restrict__ po,
    float* __restrict__ AT)
{
    __shared__ float4 w4[4][32];             // row 0, cols 0..127 of each W, pre-scaled
    float* w = reinterpret_cast<float*>(w4);
    int tid = threadIdx.x;
    for (int k = tid; k < 512; k += 256) {
        int g = k >> 7, j = k & 127;
        const float* W = (g == 0) ? Wf : (g == 1) ? Wi : (g == 2) ? Wu : Wo;
        w[g * 128 + j] = W[j] * INV2PI;
    }
    __syncthreads();

    int r = blockIdx.x * 256 + tid;          // r = t*BB + b
    int t = r >> 8, b = r & 255;
    const float4* xr = reinterpret_cast<const float4*>(x + (size_t)r * DD);

    float af = (bf[0] + pf[0]) * INV2PI;
    float ai = (bi[0] + pi[0]) * INV2PI;
    float au = (bu[0] + pu[0]) * INV2PI;
    float ao = (bo[0] + po[0]) * INV2PI;
    #pragma unroll
    for (int k = 0; k < 32; ++k) {
        float4 v  = xr[k];
        float4 f4 = w4[0][k], i4 = w4[1][k], u4 = w4[2][k], o4 = w4[3][k];
        af = fmaf(v.x, f4.x, fmaf(v.y, f4.y, fmaf(v.z, f4.z, fmaf(v.w, f4.w, af))));
        ai = fmaf(v.x, i4.x, fmaf(v.y, i4.y, fmaf(v.z, i4.z, fmaf(v.w, i4.w, ai))));
        au = fmaf(v.x, u4.x, fmaf(v.y, u4.y, fmaf(v.z, u4.z, fmaf(v.w, u4.w, au))));
        ao = fmaf(v.x, o4.x, fmaf(v.y, o4.y, fmaf(v.z, o4.z, fmaf(v.w, o4.w, ao))));
    }
    size_t o = (size_t)b * 1024 + t;         // transposed: [b][g][t]
    AT[o] = af; AT[o + 256] = ai; AT[o + 512] = au; AT[o + 768] = ao;
}

// Kernel 2: quad-per-sample recurrence. 16 blocks x 64 lanes; lane=(q<<2)|g.
// Loads: float4 = 4 steps of own gate angles; 16-step prefetch lookahead.
// Gates: act = Bq + v*(Q0 + Q1*w + Q2*w^2), v=cos(2pi*z), w=v^2 — exact 3-harmonic
// Fourier of sigma(cos)/tanh(cos) (no rcp). tanh(c): depth-4 CF Pade (one rcp).
// h stored 4-at-a-time into the consumed f-row (becomes the H buffer).
__global__ __launch_bounds__(64) void k_recur(
    float* __restrict__ AT,
    const float* __restrict__ Wf, const float* __restrict__ Wi,
    const float* __restrict__ Wu, const float* __restrict__ Wo)
{
    int lane = threadIdx.x;
    int q = lane >> 2, g = lane & 3;
    int s = blockIdx.x * 16 + q;

    // S_g = (sum Wg[0,128:256]) / 2pi (h constant over hidden dim -> scalar feedback)
    const float* W = (g == 0) ? Wf : (g == 1) ? Wi : (g == 2) ? Wu : Wo;
    const float4* W4 = reinterpret_cast<const float4*>(W + 128);
    float S = 0.f;
    #pragma unroll
    for (int k = 0; k < 32; ++k) {
        float4 v = W4[k];
        S += (v.x + v.y) + (v.z + v.w);
    }
    S *= INV2PI;

    // Fourier coefficients (Chebyshev basis in v): act = Bq + v*(Q0 + Q1*w + Q2*w^2)
    // sigmoid: 0.5 + a1*T1 + a3*T3 + a5*T5, a1=0.2355715 a3=-0.00463015 a5=0.00011016
    // tanh:          b1*T1 + b3*T3 + b5*T5, b1=0.81167   b3=-0.05425    b5=0.00452
    bool tg = (g == 2);
    float Q0 = tg ? 0.99702f   : 0.2500128f;
    float Q1 = tg ? -0.3074f   : -0.0207238f;
    float Q2 = tg ? 0.07232f   : 0.00176256f;
    float Bq = tg ? 0.f        : 0.5f;

    float* row = AT + (size_t)(s * 4 + g) * 256;              // own gate row
    const float4* Ab4 = reinterpret_cast<const float4*>(row); // 64 float4 groups
    float4* H4 = reinterpret_cast<float4*>(AT + (size_t)s * 1024); // f-row = H buffer

    float h = 0.f, c = 0.f;
    float4 P0 = Ab4[0], P1 = Ab4[1], P2 = Ab4[2], P3 = Ab4[3];

#define STEPC(AIN, HOUT)                                                      \
    {                                                                         \
        float z = fmaf(h, S, AIN);           /* revolutions */                \
        float v = __builtin_amdgcn_cosf(z);                                   \
        float w = v * v;                                                      \
        float act = fmaf(v, fmaf(w, fmaf(w, Q2, Q1), Q0), Bq);                \
        float tu = quad_bcast<2>(act);                                        \
        float ti = quad_bcast<1>(act);                                        \
        float tf = quad_bcast<0>(act);                                        \
        float to = quad_bcast<3>(act);                                        \
        c = fmaf(tf, c, ti * tu);            /* |c| <= 2.07 */                \
        float w2 = c * c;                                                     \
        float d2 = fmaf(w2, fmaf(w2, w2 + 210.f, 4725.f), 10395.f);           \
        float rd2 = frcp(d2);                                                 \
        float n2 = c * fmaf(w2, fmaf(w2, 21.f, 1260.f), 10395.f);             \
        h = (to * n2) * rd2;                                                  \
        HOUT = h;                                                             \
    }
// one float4-group: 4 steps, one 16B h-store (g==0 lane), one 16B prefetch refill
#define GROUP(P, IDX)                                                         \
    {                                                                         \
        float h0, h1, h2, h3;                                                 \
        STEPC(P.x, h0) STEPC(P.y, h1) STEPC(P.z, h2) STEPC(P.w, h3)           \
        if (g == 0) H4[IDX] = make_float4(h0, h1, h2, h3);                    \
        int nx = (IDX) + 4; nx = (nx > 63) ? 63 : nx;                         \
        P = Ab4[nx];                                                          \
    }

    #pragma unroll 1
    for (int it = 0; it < 16; ++it) {
        int i0 = it * 4;
        GROUP(P0, i0 + 0)
        GROUP(P1, i0 + 1)
        GROUP(P2, i0 + 2)
        GROUP(P3, i0 + 3)
    }
#undef GROUP
#undef STEPC
    // final c into the consumed i-row slot 255 (float index s*1024 + 511)
    if (g == 1) AT[(size_t)s * 1024 + 511] = c;
}

// Kernel 3: broadcast expand. outs[t][b][:] = H[b][t] = AT[b*1024 + t];
// hx[b][:] = AT[b*1024 + 255]; cx[b][:] = AT[b*1024 + 511]
__global__ __launch_bounds__(256) void k_expand(
    const float* __restrict__ AT, float4* __restrict__ out)
{
    unsigned r = blockIdx.x * 256 + threadIdx.x;          // one float4 of output
    const unsigned OUTS4 = (unsigned)TT * BB * 128 / 4;   // 2,097,152
    const unsigned HX4   = (unsigned)BB * 128 / 4;        // 8,192
    float v;
    if (r < OUTS4) {
        unsigned t = r >> 13, b = (r >> 5) & 255u;
        v = AT[b * 1024u + t];
    } else {
        unsigned qq = r - OUTS4;
        unsigned b = (qq & (HX4 - 1)) >> 5;
        v = (qq < HX4) ? AT[b * 1024u + 255u] : AT[b * 1024u + 511u];
    }
    out[r] = make_float4(v, v, v, v);
}

extern "C" void kernel_launch(void* const* d_in, const int* in_sizes, int n_in,
                              void* d_out, int out_size, void* d_ws, size_t ws_size,
                              hipStream_t stream) {
    const float* x = (const float*)d_in[0];
    const float *Wf, *bf, *pf, *Wi, *bi, *pi, *Wu, *bu, *pu, *Wo, *bo, *po;
    if (n_in >= 13 && in_sizes[3] == 8 && in_sizes[4] == 2048) {
        // setup_inputs dict order: (Wf,bf,pf),(Wi,bi,pi),(Wu,bu,pu),(Wo,bo,po)
        Wf = (const float*)d_in[1];  bf = (const float*)d_in[2];  pf = (const float*)d_in[3];
        Wi = (const float*)d_in[4];  bi = (const float*)d_in[5];  pi = (const float*)d_in[6];
        Wu = (const float*)d_in[7];  bu = (const float*)d_in[8];  pu = (const float*)d_in[9];
        Wo = (const float*)d_in[10]; bo = (const float*)d_in[11]; po = (const float*)d_in[12];
    } else {
        // reference signature order: Wf,bf,Wi,bi,Wu,bu,Wo,bo,pf,pi,pu,po
        Wf = (const float*)d_in[1];  bf = (const float*)d_in[2];
        Wi = (const float*)d_in[3];  bi = (const float*)d_in[4];
        Wu = (const float*)d_in[5];  bu = (const float*)d_in[6];
        Wo = (const float*)d_in[7];  bo = (const float*)d_in[8];
        pf = (const float*)d_in[9];  pi = (const float*)d_in[10];
        pu = (const float*)d_in[11]; po = (const float*)d_in[12];
    }
    float* AT = (float*)d_ws;                  // 262144 floats = 1 MiB scratch

    k_angles<<<dim3(256), dim3(256), 0, stream>>>(
        x, Wf, bf, pf, Wi, bi, pi, Wu, bu, pu, Wo, bo, po, AT);
    k_recur<<<dim3(16), dim3(64), 0, stream>>>(AT, Wf, Wi, Wu, Wo);
    k_expand<<<dim3((TT * BB * 128 / 4 + 2 * BB * 128 / 4) / 256), dim3(256), 0, stream>>>(
        AT, (float4*)d_out);
}